// Round 2
// baseline (3605.757 us; speedup 1.0000x reference)
//
#include <hip/hip_runtime.h>
#include <cmath>

#define LSEQ 2048
#define NBATCH 8

__device__ __forceinline__ float silu_f(float x) {
    return x / (1.0f + __expf(-x));
}

__device__ __forceinline__ float softplus_f(float x) {
    return fmaxf(x, 0.0f) + log1pf(__expf(-fabsf(x)));
}

// ---------------------------------------------------------------------------
// Generic tiled fp32 GEMM:  C[m,n] = act( sum_k A[m*lda+k] * W[n*ldw+k] + bias[n] )
// Tile 64x64, BK=16, 256 threads, 4x4 per thread. M,N implied by grid (both %64==0).
// ACT: 0 = none, 1 = softplus
// ---------------------------------------------------------------------------
template<int ACT>
__global__ __launch_bounds__(256) void gemm_nt(const float* __restrict__ A, int lda,
                                               const float* __restrict__ W, int ldw,
                                               const float* __restrict__ bias,
                                               float* __restrict__ C, int ldc, int K)
{
    __shared__ __align__(16) float As[16][68];
    __shared__ __align__(16) float Ws[16][68];
    const int tid = threadIdx.x;
    const int m0 = blockIdx.y * 64;
    const int n0 = blockIdx.x * 64;
    const int tm = tid >> 4;           // 0..15
    const int tn = tid & 15;           // 0..15
    const int lr = tid >> 2;           // 0..63
    const int lc = (tid & 3) << 2;     // 0,4,8,12

    float acc[4][4] = {};

    const float* Ap = A + (size_t)(m0 + lr) * lda + lc;
    const float* Wp = W + (size_t)(n0 + lr) * ldw + lc;

    for (int k0 = 0; k0 < K; k0 += 16) {
        const float4 av = *(const float4*)(Ap + k0);
        const float4 wv = *(const float4*)(Wp + k0);
        __syncthreads();
        As[lc + 0][lr] = av.x; As[lc + 1][lr] = av.y; As[lc + 2][lr] = av.z; As[lc + 3][lr] = av.w;
        Ws[lc + 0][lr] = wv.x; Ws[lc + 1][lr] = wv.y; Ws[lc + 2][lr] = wv.z; Ws[lc + 3][lr] = wv.w;
        __syncthreads();
#pragma unroll
        for (int k = 0; k < 16; ++k) {
            const float4 a = *(const float4*)&As[k][tm << 2];
            const float4 b = *(const float4*)&Ws[k][tn << 2];
            acc[0][0] += a.x * b.x; acc[0][1] += a.x * b.y; acc[0][2] += a.x * b.z; acc[0][3] += a.x * b.w;
            acc[1][0] += a.y * b.x; acc[1][1] += a.y * b.y; acc[1][2] += a.y * b.z; acc[1][3] += a.y * b.w;
            acc[2][0] += a.z * b.x; acc[2][1] += a.z * b.y; acc[2][2] += a.z * b.z; acc[2][3] += a.z * b.w;
            acc[3][0] += a.w * b.x; acc[3][1] += a.w * b.y; acc[3][2] += a.w * b.z; acc[3][3] += a.w * b.w;
        }
    }

    float4 bb = make_float4(0.f, 0.f, 0.f, 0.f);
    if (bias) bb = *(const float4*)&bias[n0 + (tn << 2)];
#pragma unroll
    for (int i = 0; i < 4; ++i) {
        float4 r;
        r.x = acc[i][0] + bb.x; r.y = acc[i][1] + bb.y;
        r.z = acc[i][2] + bb.z; r.w = acc[i][3] + bb.w;
        if (ACT == 1) {
            r.x = softplus_f(r.x); r.y = softplus_f(r.y);
            r.z = softplus_f(r.z); r.w = softplus_f(r.w);
        }
        *(float4*)&C[(size_t)(m0 + (tm << 2) + i) * ldc + n0 + (tn << 2)] = r;
    }
}

// ---------------------------------------------------------------------------
// Final merge: out[m,n] = o_f[m,:]@lin_w[n,:512]^T + o_b[m^2047,:]@lin_w[n,512:]^T + lin_b[n]
// m is group-local; o_b is in reversed-time coords (XOR 2047 un-reverses t in-batch).
// ---------------------------------------------------------------------------
__global__ __launch_bounds__(256) void gemm_final_k(const float* __restrict__ A1,
                                                    const float* __restrict__ A2,
                                                    const float* __restrict__ W,    // lin_w (512,1024)
                                                    const float* __restrict__ bias, // lin_b (512)
                                                    float* __restrict__ C)
{
    __shared__ __align__(16) float As[16][68];
    __shared__ __align__(16) float Ws[16][68];
    const int tid = threadIdx.x;
    const int m0 = blockIdx.y * 64;
    const int n0 = blockIdx.x * 64;
    const int tm = tid >> 4;
    const int tn = tid & 15;
    const int lr = tid >> 2;
    const int lc = (tid & 3) << 2;

    float acc[4][4] = {};

    for (int ph = 0; ph < 2; ++ph) {
        const float* A = ph ? A2 : A1;
        const int arow = ph ? ((m0 + lr) ^ (LSEQ - 1)) : (m0 + lr);
        const float* Ap = A + (size_t)arow * 512 + lc;
        const float* Wp = W + (size_t)(n0 + lr) * 1024 + ph * 512 + lc;
        for (int k0 = 0; k0 < 512; k0 += 16) {
            const float4 av = *(const float4*)(Ap + k0);
            const float4 wv = *(const float4*)(Wp + k0);
            __syncthreads();
            As[lc + 0][lr] = av.x; As[lc + 1][lr] = av.y; As[lc + 2][lr] = av.z; As[lc + 3][lr] = av.w;
            Ws[lc + 0][lr] = wv.x; Ws[lc + 1][lr] = wv.y; Ws[lc + 2][lr] = wv.z; Ws[lc + 3][lr] = wv.w;
            __syncthreads();
#pragma unroll
            for (int k = 0; k < 16; ++k) {
                const float4 a = *(const float4*)&As[k][tm << 2];
                const float4 b = *(const float4*)&Ws[k][tn << 2];
                acc[0][0] += a.x * b.x; acc[0][1] += a.x * b.y; acc[0][2] += a.x * b.z; acc[0][3] += a.x * b.w;
                acc[1][0] += a.y * b.x; acc[1][1] += a.y * b.y; acc[1][2] += a.y * b.z; acc[1][3] += a.y * b.w;
                acc[2][0] += a.z * b.x; acc[2][1] += a.z * b.y; acc[2][2] += a.z * b.z; acc[2][3] += a.z * b.w;
                acc[3][0] += a.w * b.x; acc[3][1] += a.w * b.y; acc[3][2] += a.w * b.z; acc[3][3] += a.w * b.w;
            }
        }
    }

    const float4 bb = *(const float4*)&bias[n0 + (tn << 2)];
#pragma unroll
    for (int i = 0; i < 4; ++i) {
        float4 r;
        r.x = acc[i][0] + bb.x; r.y = acc[i][1] + bb.y;
        r.z = acc[i][2] + bb.z; r.w = acc[i][3] + bb.w;
        *(float4*)&C[(size_t)(m0 + (tm << 2) + i) * 512 + n0 + (tn << 2)] = r;
    }
}

// ---------------------------------------------------------------------------
// Causal depthwise conv(4) + bias + SiLU, both directions in one launch.
// xc buffers are (rows x 1024). Backward dir indexes reversed rows of xc_b.
// ---------------------------------------------------------------------------
__global__ __launch_bounds__(256) void conv_silu_k(
    const float* __restrict__ xc_f, const float* __restrict__ cw_f,
    const float* __restrict__ cb_f, float* __restrict__ xi_f,
    const float* __restrict__ xc_b, const float* __restrict__ cw_b,
    const float* __restrict__ cb_b, float* __restrict__ xi_b)
{
    const int dir = blockIdx.y;
    const float* xc = dir ? xc_b : xc_f;
    const float* cw = dir ? cw_b : cw_f;
    const float* cb = dir ? cb_b : cb_f;
    float* xi       = dir ? xi_b : xi_f;

    const int bt = blockIdx.x;
    const int b = bt >> 11;          // group-local batch
    const int t = bt & (LSEQ - 1);
    const int d = threadIdx.x << 2;

    float w[4][4];
#pragma unroll
    for (int i = 0; i < 4; ++i) {
        const float4 wr = *(const float4*)&cw[(d + i) * 4];
        w[i][0] = wr.x; w[i][1] = wr.y; w[i][2] = wr.z; w[i][3] = wr.w;
    }
    float4 acc = *(const float4*)&cb[d];
#pragma unroll
    for (int k = 0; k < 4; ++k) {
        const int row = dir ? (LSEQ - 1 - t) + 3 - k : t - 3 + k;
        if ((unsigned)row < (unsigned)LSEQ) {
            const float4 v = *(const float4*)&xc[(size_t)(b * LSEQ + row) * 1024 + d];
            acc.x += w[0][k] * v.x; acc.y += w[1][k] * v.y;
            acc.z += w[2][k] * v.z; acc.w += w[3][k] * v.w;
        }
    }
    acc.x = silu_f(acc.x); acc.y = silu_f(acc.y);
    acc.z = silu_f(acc.z); acc.w = silu_f(acc.w);
    *(float4*)&xi[(size_t)(b * LSEQ + t) * 1024 + d] = acc;
}

// ---------------------------------------------------------------------------
// Selective scan, both directions (blockIdx.z). 256 threads = 16 ch x 16 states.
// h = exp(dt*A)*h + dt*x*B ; y = sum_n h*C (shfl width-16);
// epilogue y = (y + xi*Dp)*silu(z), written IN PLACE over the dt buffer
// (block exclusively owns its (batch, 16-channel) slice for all t -> race-free).
// z buffer is (rows x 1024); dir 1 reads z at reversed row within the batch.
// ---------------------------------------------------------------------------
__global__ __launch_bounds__(256) void scan_k(
    float* __restrict__ dty_f, const float* __restrict__ xi_f,
    const float* __restrict__ dbl_f, const float* __restrict__ z_f,
    const float* __restrict__ Al_f, const float* __restrict__ Dp_f,
    float* __restrict__ dty_b, const float* __restrict__ xi_b,
    const float* __restrict__ dbl_b, const float* __restrict__ z_b,
    const float* __restrict__ Al_b, const float* __restrict__ Dp_b)
{
    __shared__ __align__(16) float sdt[64][16];
    __shared__ __align__(16) float sxi[64][16];
    __shared__ __align__(16) float sB[64][16];
    __shared__ __align__(16) float sC[64][16];
    __shared__ __align__(16) float sz[64][16];
    __shared__ __align__(16) float sy[64][16];

    const int dir = blockIdx.z;
    float*       dty = dir ? dty_b : dty_f;
    const float* xi  = dir ? xi_b  : xi_f;
    const float* dbl = dir ? dbl_b : dbl_f;
    const float* zz  = dir ? z_b   : z_f;
    const float* Al  = dir ? Al_b  : Al_f;
    const float* Dpp = dir ? Dp_b  : Dp_f;

    const int b  = blockIdx.y;       // group-local batch
    const int d0 = blockIdx.x << 4;
    const int tid = threadIdx.x;
    const int di = tid >> 4;         // channel in group: 0..15
    const int n  = tid & 15;         // state: 0..15
    const int d  = d0 + di;

    const float Av = -expf(Al[d * 16 + n]);
    const float dp = Dpp[d];

    const int lr = tid >> 2;         // timestep within chunk 0..63
    const int lc = (tid & 3) << 2;   // 0,4,8,12

    float h = 0.0f;

    for (int t0 = 0; t0 < LSEQ; t0 += 64) {
        __syncthreads();
        const size_t rbase = (size_t)(b * LSEQ + t0 + lr);
        *(float4*)&sdt[lr][lc] = *(const float4*)&dty[rbase * 1024 + d0 + lc];
        *(float4*)&sxi[lr][lc] = *(const float4*)&xi[rbase * 1024 + d0 + lc];
        *(float4*)&sB[lr][lc]  = *(const float4*)&dbl[rbase * 64 + 32 + lc];
        *(float4*)&sC[lr][lc]  = *(const float4*)&dbl[rbase * 64 + 48 + lc];
        const int tz = dir ? (LSEQ - 1 - (t0 + lr)) : (t0 + lr);
        *(float4*)&sz[lr][lc]  = *(const float4*)&zz[(size_t)(b * LSEQ + tz) * 1024 + d0 + lc];
        __syncthreads();

        for (int tt = 0; tt < 64; ++tt) {
            const float dtv = sdt[tt][di];
            const float xiv = sxi[tt][di];
            const float bv  = sB[tt][n];
            const float cv  = sC[tt][n];
            h = __expf(dtv * Av) * h + (dtv * xiv) * bv;
            float p = h * cv;
            p += __shfl_xor(p, 1, 16);
            p += __shfl_xor(p, 2, 16);
            p += __shfl_xor(p, 4, 16);
            p += __shfl_xor(p, 8, 16);
            if (n == 0) {
                const float zv = sz[tt][di];
                sy[tt][di] = (p + xiv * dp) * silu_f(zv);
            }
        }
        __syncthreads();
        *(float4*)&dty[rbase * 1024 + d0 + lc] = *(const float4*)&sy[lr][lc];
    }
}

// ---------------------------------------------------------------------------
extern "C" void kernel_launch(void* const* d_in, const int* in_sizes, int n_in,
                              void* d_out, int out_size, void* d_ws, size_t ws_size,
                              hipStream_t stream)
{
    const float* x      = (const float*)d_in[0];
    const float* f_in_w = (const float*)d_in[1];
    const float* f_cw   = (const float*)d_in[2];
    const float* f_cb   = (const float*)d_in[3];
    const float* f_xp   = (const float*)d_in[4];
    const float* f_dtw  = (const float*)d_in[5];
    const float* f_dtb  = (const float*)d_in[6];
    const float* f_Al   = (const float*)d_in[7];
    const float* f_Dp   = (const float*)d_in[8];
    const float* f_ow   = (const float*)d_in[9];
    const float* b_in_w = (const float*)d_in[10];
    const float* b_cw   = (const float*)d_in[11];
    const float* b_cb   = (const float*)d_in[12];
    const float* b_xp   = (const float*)d_in[13];
    const float* b_dtw  = (const float*)d_in[14];
    const float* b_dtb  = (const float*)d_in[15];
    const float* b_Al   = (const float*)d_in[16];
    const float* b_Dp   = (const float*)d_in[17];
    const float* b_ow   = (const float*)d_in[18];
    const float* lin_w  = (const float*)d_in[19];
    const float* lin_b  = (const float*)d_in[20];
    float* out = (float*)d_out;

    // Pick largest batch-group G in {8,4,2,1} whose workspace fits ws_size.
    // Per group: per dir xc(1024) + z(1024) + xi(1024) + dbl(64) floats/row.
    int G = 1;
    for (int g = 8; g >= 1; g >>= 1) {
        size_t need = (size_t)g * LSEQ * (3 * 1024 + 64) * 4 * 2;
        if (need <= ws_size) { G = g; break; }
        if (g == 1) G = 1;  // no smaller option; run anyway
    }

    const dim3 blk(256);

    for (int g0 = 0; g0 < NBATCH; g0 += G) {
        const int Mg = G * LSEQ;                 // rows in this group
        const float* xg = x + (size_t)g0 * LSEQ * 512;
        float* outg = out + (size_t)g0 * LSEQ * 512;

        float* p = (float*)d_ws;
        float* xc_f  = p; p += (size_t)Mg * 1024;   // later reused as dt then y (fwd)
        float* z_f   = p; p += (size_t)Mg * 1024;
        float* xi_f  = p; p += (size_t)Mg * 1024;   // later reused as o_f
        float* dbl_f = p; p += (size_t)Mg * 64;
        float* xc_b  = p; p += (size_t)Mg * 1024;
        float* z_b   = p; p += (size_t)Mg * 1024;
        float* xi_b  = p; p += (size_t)Mg * 1024;   // later reused as o_b
        float* dbl_b = p; p += (size_t)Mg * 64;

        // in-proj: x-part -> xc, z-part -> z (W row offset 1024)
        gemm_nt<0><<<dim3(16, Mg / 64), blk, 0, stream>>>(xg, 512, f_in_w, 512, nullptr, xc_f, 1024, 512);
        gemm_nt<0><<<dim3(16, Mg / 64), blk, 0, stream>>>(xg, 512, f_in_w + (size_t)1024 * 512, 512, nullptr, z_f, 1024, 512);
        gemm_nt<0><<<dim3(16, Mg / 64), blk, 0, stream>>>(xg, 512, b_in_w, 512, nullptr, xc_b, 1024, 512);
        gemm_nt<0><<<dim3(16, Mg / 64), blk, 0, stream>>>(xg, 512, b_in_w + (size_t)1024 * 512, 512, nullptr, z_b, 1024, 512);

        // conv + SiLU (bwd output in reversed-time coords)
        conv_silu_k<<<dim3(Mg, 2), blk, 0, stream>>>(xc_f, f_cw, f_cb, xi_f, xc_b, b_cw, b_cb, xi_b);

        // x-proj: dbl = xi @ xp_w^T   (Mg x 64, K=1024)
        gemm_nt<0><<<dim3(1, Mg / 64), blk, 0, stream>>>(xi_f, 1024, f_xp, 1024, nullptr, dbl_f, 64, 1024);
        gemm_nt<0><<<dim3(1, Mg / 64), blk, 0, stream>>>(xi_b, 1024, b_xp, 1024, nullptr, dbl_b, 64, 1024);

        // dt = softplus(dbl[:, :32] @ dt_w^T + dt_b) -> overwrite dead xc
        gemm_nt<1><<<dim3(16, Mg / 64), blk, 0, stream>>>(dbl_f, 64, f_dtw, 32, f_dtb, xc_f, 1024, 32);
        gemm_nt<1><<<dim3(16, Mg / 64), blk, 0, stream>>>(dbl_b, 64, b_dtw, 32, b_dtb, xc_b, 1024, 32);

        // selective scan + gate; writes gated y in place over dt(xc)
        scan_k<<<dim3(64, G, 2), blk, 0, stream>>>(xc_f, xi_f, dbl_f, z_f, f_Al, f_Dp,
                                                   xc_b, xi_b, dbl_b, z_b, b_Al, b_Dp);

        // out-proj: o = y @ out_w^T -> overwrite dead xi
        gemm_nt<0><<<dim3(8, Mg / 64), blk, 0, stream>>>(xc_f, 1024, f_ow, 1024, nullptr, xi_f, 512, 1024);
        gemm_nt<0><<<dim3(8, Mg / 64), blk, 0, stream>>>(xc_b, 1024, b_ow, 1024, nullptr, xi_b, 512, 1024);

        // final merge
        gemm_final_k<<<dim3(8, Mg / 64), blk, 0, stream>>>(xi_f, xi_b, lin_w, lin_b, outg);
    }
}

// Round 3
// 1244.032 us; speedup vs baseline: 2.8984x; 2.8984x over previous
//
#include <hip/hip_runtime.h>
#include <cmath>

#define LSEQ 2048
#define NBATCH 8

typedef __attribute__((ext_vector_type(8))) short short8;
typedef __attribute__((ext_vector_type(4))) float f32x4;

__device__ __forceinline__ float silu_f(float x) { return x / (1.0f + __expf(-x)); }
__device__ __forceinline__ float softplus_f(float x) {
    return fmaxf(x, 0.0f) + log1pf(__expf(-fabsf(x)));
}
__device__ __forceinline__ unsigned short f2bf(float f) {   // RNE fp32->bf16
    unsigned int u = __float_as_uint(f);
    u += 0x7FFFu + ((u >> 16) & 1u);
    return (unsigned short)(u >> 16);
}
__device__ __forceinline__ float bf2f(unsigned short h) {
    return __uint_as_float(((unsigned int)h) << 16);
}
__device__ __forceinline__ void gload_lds16(const void* g, void* l) {
    __builtin_amdgcn_global_load_lds((const __attribute__((address_space(1))) void*)g,
                                     (__attribute__((address_space(3))) void*)l, 16, 0, 0);
}
// sum over 16-lane row via DPP (VALU pipe, no DS traffic)
__device__ __forceinline__ float row_sum16(float x) {
    x += __int_as_float(__builtin_amdgcn_update_dpp(0, __float_as_int(x), 0xB1, 0xF, 0xF, false));  // quad xor1
    x += __int_as_float(__builtin_amdgcn_update_dpp(0, __float_as_int(x), 0x4E, 0xF, 0xF, false));  // quad xor2
    x += __int_as_float(__builtin_amdgcn_update_dpp(0, __float_as_int(x), 0x141, 0xF, 0xF, false)); // row_half_mirror
    x += __int_as_float(__builtin_amdgcn_update_dpp(0, __float_as_int(x), 0x140, 0xF, 0xF, false)); // row_mirror
    return x;
}

// ---------------------------------------------------------------------------
// bf16 MFMA GEMM (NT): C[m,n] = act( A[m,:].W[n,:] + bias[n] )
// Block 256 = 4 waves; each wave 64x64 via 4x4 of mfma_f32_16x16x32_bf16.
// Tile TM=WM*64, TN=WN*64, BK=32, global_load_lds width-16 staging.
// OMODE: 0=f32 out, 1=bf16 out, 2=f32 out + softplus. DUAL: A2 is second K-half
// with row reversed per batch (final merge). XTRA: also write bf16 of cols<32.
// ---------------------------------------------------------------------------
template<int WM, int WN, int OMODE, int DUAL, int XTRA>
__global__ __launch_bounds__(256) void gemm_mfma(
    const unsigned short* __restrict__ A, int lda,
    const unsigned short* __restrict__ A2,
    const unsigned short* __restrict__ W, int ldw,
    const float* __restrict__ bias,
    void* __restrict__ Cout, int ldc,
    unsigned short* __restrict__ aux, int K)
{
    constexpr int TM = WM * 64, TN = WN * 64;
    __shared__ unsigned short As[TM * 32];
    __shared__ unsigned short Bs[TN * 32];
    const int tid = threadIdx.x;
    const int wave = tid >> 6, lane = tid & 63;
    const int wm = (WN == 1) ? wave : (wave >> 1);
    const int wn = (WN == 1) ? 0 : (wave & 1);
    const int m0 = blockIdx.y * TM, n0 = blockIdx.x * TN;
    const int l15 = lane & 15, l4 = lane >> 4;
    const int srow = lane >> 2, schunk = (lane & 3) * 8;

    f32x4 acc[4][4] = {};

    for (int k0 = 0; k0 < K; k0 += 32) {
        __syncthreads();
        for (int s = wave; s < TM / 16; s += 4) {
            const int gr = m0 + s * 16 + srow;
            const unsigned short* g;
            if (DUAL && k0 >= 512)
                g = A2 + (size_t)(gr ^ (LSEQ - 1)) * 512 + (k0 - 512) + schunk;
            else
                g = A + (size_t)gr * lda + k0 + schunk;
            gload_lds16(g, (char*)As + (size_t)s * 1024);
        }
        for (int s = wave; s < TN / 16; s += 4) {
            const int gr = n0 + s * 16 + srow;
            const unsigned short* g = W + (size_t)gr * ldw + k0 + schunk;
            gload_lds16(g, (char*)Bs + (size_t)s * 1024);
        }
        __syncthreads();
        short8 af[4], bfr[4];
#pragma unroll
        for (int mi = 0; mi < 4; ++mi)
            af[mi] = *(const short8*)&As[(wm * 64 + mi * 16 + l15) * 32 + l4 * 8];
#pragma unroll
        for (int ni = 0; ni < 4; ++ni)
            bfr[ni] = *(const short8*)&Bs[(wn * 64 + ni * 16 + l15) * 32 + l4 * 8];
#pragma unroll
        for (int mi = 0; mi < 4; ++mi)
#pragma unroll
            for (int ni = 0; ni < 4; ++ni)
                acc[mi][ni] = __builtin_amdgcn_mfma_f32_16x16x32_bf16(af[mi], bfr[ni], acc[mi][ni], 0, 0, 0);
    }

#pragma unroll
    for (int mi = 0; mi < 4; ++mi)
#pragma unroll
        for (int ni = 0; ni < 4; ++ni)
#pragma unroll
            for (int r = 0; r < 4; ++r) {
                const int row = m0 + wm * 64 + mi * 16 + l4 * 4 + r;
                const int col = n0 + wn * 64 + ni * 16 + l15;
                float v = acc[mi][ni][r];
                if (bias) v += bias[col];
                if (OMODE == 2) v = softplus_f(v);
                if (OMODE == 1) ((unsigned short*)Cout)[(size_t)row * ldc + col] = f2bf(v);
                else            ((float*)Cout)[(size_t)row * ldc + col] = v;
                if (XTRA) { if (col < 32) aux[(size_t)row * 32 + col] = f2bf(v); }
            }
}

// ---------------------------------------------------------------------------
// fp32 -> bf16 conversion: 9 weight segments, one launch.
// ---------------------------------------------------------------------------
struct CvtArgs { const float* s[9]; unsigned short* d[9]; int n[9]; };
__global__ __launch_bounds__(256) void cvt_k(CvtArgs a)
{
    const int sid = blockIdx.y;
    const float* s = a.s[sid];
    unsigned short* d = a.d[sid];
    const int n4 = a.n[sid] >> 2;
    for (int i = blockIdx.x * 256 + threadIdx.x; i < n4; i += gridDim.x * 256) {
        const float4 v = ((const float4*)s)[i];
        ushort4 o; o.x = f2bf(v.x); o.y = f2bf(v.y); o.z = f2bf(v.z); o.w = f2bf(v.w);
        ((ushort4*)d)[i] = o;
    }
}
__global__ __launch_bounds__(256) void cvtx_k(const float* __restrict__ s,
                                              unsigned short* __restrict__ d, int n4)
{
    for (int i = blockIdx.x * 256 + threadIdx.x; i < n4; i += gridDim.x * 256) {
        const float4 v = ((const float4*)s)[i];
        ushort4 o; o.x = f2bf(v.x); o.y = f2bf(v.y); o.z = f2bf(v.z); o.w = f2bf(v.w);
        ((ushort4*)d)[i] = o;
    }
}

// ---------------------------------------------------------------------------
// Causal depthwise conv(4) + bias + SiLU, both dirs; fp32 in, bf16 out.
// ---------------------------------------------------------------------------
__global__ __launch_bounds__(256) void conv_silu_k(
    const float* __restrict__ xc_f, const float* __restrict__ cw_f,
    const float* __restrict__ cb_f, unsigned short* __restrict__ xi_f,
    const float* __restrict__ xc_b, const float* __restrict__ cw_b,
    const float* __restrict__ cb_b, unsigned short* __restrict__ xi_b)
{
    const int dir = blockIdx.y;
    const float* xc = dir ? xc_b : xc_f;
    const float* cw = dir ? cw_b : cw_f;
    const float* cb = dir ? cb_b : cb_f;
    unsigned short* xi = dir ? xi_b : xi_f;

    const int bt = blockIdx.x;
    const int b = bt >> 11;
    const int t = bt & (LSEQ - 1);
    const int d = threadIdx.x << 2;

    float w[4][4];
#pragma unroll
    for (int i = 0; i < 4; ++i) {
        const float4 wr = *(const float4*)&cw[(d + i) * 4];
        w[i][0] = wr.x; w[i][1] = wr.y; w[i][2] = wr.z; w[i][3] = wr.w;
    }
    float4 acc = *(const float4*)&cb[d];
#pragma unroll
    for (int k = 0; k < 4; ++k) {
        const int row = dir ? (LSEQ - 1 - t) + 3 - k : t - 3 + k;
        if ((unsigned)row < (unsigned)LSEQ) {
            const float4 v = *(const float4*)&xc[(size_t)(b * LSEQ + row) * 1024 + d];
            acc.x += w[0][k] * v.x; acc.y += w[1][k] * v.y;
            acc.z += w[2][k] * v.z; acc.w += w[3][k] * v.w;
        }
    }
    ushort4 st;
    st.x = f2bf(silu_f(acc.x)); st.y = f2bf(silu_f(acc.y));
    st.z = f2bf(silu_f(acc.z)); st.w = f2bf(silu_f(acc.w));
    *(ushort4*)&xi[(size_t)(b * LSEQ + t) * 1024 + d] = st;
}

// ---------------------------------------------------------------------------
// Selective scan. 256 thr = 16 ch x 16 states. Transposed LDS [ch][t] ->
// ds_read_b128 over 4 timesteps; reduction over states via DPP (VALU).
// Writes gated y (bf16) in place over xi. z read fp32 at writeback.
// ---------------------------------------------------------------------------
__global__ __launch_bounds__(256) void scan_k(
    const float* __restrict__ dt_f, unsigned short* __restrict__ xiy_f,
    const float* __restrict__ dbl_f, const float* __restrict__ z_f,
    const float* __restrict__ Al_f, const float* __restrict__ Dp_f,
    const float* __restrict__ dt_b, unsigned short* __restrict__ xiy_b,
    const float* __restrict__ dbl_b, const float* __restrict__ z_b,
    const float* __restrict__ Al_b, const float* __restrict__ Dp_b)
{
    __shared__ float sdt[16][68], sxi[16][68], sB[16][68], sC[16][68], sy[16][68];

    const int dir = blockIdx.z;
    const float* dt = dir ? dt_b : dt_f;
    unsigned short* xiy = dir ? xiy_b : xiy_f;
    const float* dbl = dir ? dbl_b : dbl_f;
    const float* zz = dir ? z_b : z_f;
    const float* Al = dir ? Al_b : Al_f;
    const float* Dpp = dir ? Dp_b : Dp_f;

    const int b = blockIdx.y, d0 = blockIdx.x << 4;
    const int tid = threadIdx.x;
    const int di = tid >> 4, n = tid & 15;
    const float Av = -expf(Al[(d0 + di) * 16 + n]);
    const int lr = tid >> 2, lc4 = (tid & 3) << 2;
    float dpv[4];
#pragma unroll
    for (int i = 0; i < 4; ++i) dpv[i] = Dpp[d0 + lc4 + i];

    float h = 0.0f;
    for (int t0 = 0; t0 < LSEQ; t0 += 64) {
        __syncthreads();
        const size_t r = (size_t)b * LSEQ + t0 + lr;
        const float4 dv = *(const float4*)&dt[r * 1024 + d0 + lc4];
        const ushort4 xv = *(const ushort4*)&xiy[r * 1024 + d0 + lc4];
        const float4 bv = *(const float4*)&dbl[r * 64 + 32 + lc4];
        const float4 cv = *(const float4*)&dbl[r * 64 + 48 + lc4];
        sdt[lc4 + 0][lr] = dv.x; sdt[lc4 + 1][lr] = dv.y; sdt[lc4 + 2][lr] = dv.z; sdt[lc4 + 3][lr] = dv.w;
        sxi[lc4 + 0][lr] = bf2f(xv.x); sxi[lc4 + 1][lr] = bf2f(xv.y);
        sxi[lc4 + 2][lr] = bf2f(xv.z); sxi[lc4 + 3][lr] = bf2f(xv.w);
        sB[lc4 + 0][lr] = bv.x; sB[lc4 + 1][lr] = bv.y; sB[lc4 + 2][lr] = bv.z; sB[lc4 + 3][lr] = bv.w;
        sC[lc4 + 0][lr] = cv.x; sC[lc4 + 1][lr] = cv.y; sC[lc4 + 2][lr] = cv.z; sC[lc4 + 3][lr] = cv.w;
        __syncthreads();

#pragma unroll
        for (int tt = 0; tt < 64; tt += 4) {
            const float4 d4 = *(const float4*)&sdt[di][tt];
            const float4 x4 = *(const float4*)&sxi[di][tt];
            const float4 b4 = *(const float4*)&sB[n][tt];
            const float4 c4 = *(const float4*)&sC[n][tt];
            {
                h = fmaf(__expf(d4.x * Av), h, d4.x * x4.x * b4.x);
                const float pp = row_sum16(h * c4.x);
                if (n == 0) sy[di][tt + 0] = pp;
            }
            {
                h = fmaf(__expf(d4.y * Av), h, d4.y * x4.y * b4.y);
                const float pp = row_sum16(h * c4.y);
                if (n == 0) sy[di][tt + 1] = pp;
            }
            {
                h = fmaf(__expf(d4.z * Av), h, d4.z * x4.z * b4.z);
                const float pp = row_sum16(h * c4.z);
                if (n == 0) sy[di][tt + 2] = pp;
            }
            {
                h = fmaf(__expf(d4.w * Av), h, d4.w * x4.w * b4.w);
                const float pp = row_sum16(h * c4.w);
                if (n == 0) sy[di][tt + 3] = pp;
            }
        }
        __syncthreads();

        float4 y4, xi4;
        y4.x = sy[lc4 + 0][lr]; y4.y = sy[lc4 + 1][lr]; y4.z = sy[lc4 + 2][lr]; y4.w = sy[lc4 + 3][lr];
        xi4.x = sxi[lc4 + 0][lr]; xi4.y = sxi[lc4 + 1][lr]; xi4.z = sxi[lc4 + 2][lr]; xi4.w = sxi[lc4 + 3][lr];
        const int tz = dir ? (LSEQ - 1 - (t0 + lr)) : (t0 + lr);
        const float4 z4 = *(const float4*)&zz[((size_t)b * LSEQ + tz) * 1024 + d0 + lc4];
        ushort4 st;
        st.x = f2bf((y4.x + xi4.x * dpv[0]) * silu_f(z4.x));
        st.y = f2bf((y4.y + xi4.y * dpv[1]) * silu_f(z4.y));
        st.z = f2bf((y4.z + xi4.z * dpv[2]) * silu_f(z4.z));
        st.w = f2bf((y4.w + xi4.w * dpv[3]) * silu_f(z4.w));
        *(ushort4*)&xiy[r * 1024 + d0 + lc4] = st;
    }
}

// ---------------------------------------------------------------------------
extern "C" void kernel_launch(void* const* d_in, const int* in_sizes, int n_in,
                              void* d_out, int out_size, void* d_ws, size_t ws_size,
                              hipStream_t stream)
{
    const float* x      = (const float*)d_in[0];
    const float* f_in_w = (const float*)d_in[1];
    const float* f_cw   = (const float*)d_in[2];
    const float* f_cb   = (const float*)d_in[3];
    const float* f_xp   = (const float*)d_in[4];
    const float* f_dtw  = (const float*)d_in[5];
    const float* f_dtb  = (const float*)d_in[6];
    const float* f_Al   = (const float*)d_in[7];
    const float* f_Dp   = (const float*)d_in[8];
    const float* f_ow   = (const float*)d_in[9];
    const float* b_in_w = (const float*)d_in[10];
    const float* b_cw   = (const float*)d_in[11];
    const float* b_cb   = (const float*)d_in[12];
    const float* b_xp   = (const float*)d_in[13];
    const float* b_dtw  = (const float*)d_in[14];
    const float* b_dtb  = (const float*)d_in[15];
    const float* b_Al   = (const float*)d_in[16];
    const float* b_Dp   = (const float*)d_in[17];
    const float* b_ow   = (const float*)d_in[18];
    const float* lin_w  = (const float*)d_in[19];
    const float* lin_b  = (const float*)d_in[20];
    float* out = (float*)d_out;

    char* p = (char*)d_ws;
    auto take = [&](size_t bytes) -> char* {
        char* r = p; p += (bytes + 255) & ~(size_t)255; return r;
    };

    // persistent bf16 weights
    unsigned short* wif  = (unsigned short*)take((size_t)2048 * 512 * 2);
    unsigned short* wib  = (unsigned short*)take((size_t)2048 * 512 * 2);
    unsigned short* wxf  = (unsigned short*)take((size_t)64 * 1024 * 2);
    unsigned short* wxb  = (unsigned short*)take((size_t)64 * 1024 * 2);
    unsigned short* wof  = (unsigned short*)take((size_t)512 * 1024 * 2);
    unsigned short* wob  = (unsigned short*)take((size_t)512 * 1024 * 2);
    unsigned short* wlin = (unsigned short*)take((size_t)512 * 1024 * 2);
    unsigned short* wdtf = (unsigned short*)take((size_t)1024 * 32 * 2);
    unsigned short* wdtb = (unsigned short*)take((size_t)1024 * 32 * 2);

    const size_t used = (size_t)(p - (char*)d_ws);
    // per-row bytes (both dirs): xbf 1024 + 2*(xc 4096 + z 4096 + xiy 2048 + dbl 256 + dblh 64 + o 1024)
    const size_t perRow = 1024 + 2 * (4096 + 4096 + 2048 + 256 + 64 + 1024);
    int G = 1;
    for (int g = 8; g >= 1; g >>= 1) {
        const size_t need = used + (size_t)g * LSEQ * perRow + 16384;
        if (need <= ws_size || g == 1) { G = g; break; }
    }

    CvtArgs ca;
    ca.s[0] = f_in_w; ca.d[0] = wif;  ca.n[0] = 2048 * 512;
    ca.s[1] = b_in_w; ca.d[1] = wib;  ca.n[1] = 2048 * 512;
    ca.s[2] = f_xp;   ca.d[2] = wxf;  ca.n[2] = 64 * 1024;
    ca.s[3] = b_xp;   ca.d[3] = wxb;  ca.n[3] = 64 * 1024;
    ca.s[4] = f_ow;   ca.d[4] = wof;  ca.n[4] = 512 * 1024;
    ca.s[5] = b_ow;   ca.d[5] = wob;  ca.n[5] = 512 * 1024;
    ca.s[6] = lin_w;  ca.d[6] = wlin; ca.n[6] = 512 * 1024;
    ca.s[7] = f_dtw;  ca.d[7] = wdtf; ca.n[7] = 1024 * 32;
    ca.s[8] = b_dtw;  ca.d[8] = wdtb; ca.n[8] = 1024 * 32;
    cvt_k<<<dim3(256, 9), 256, 0, stream>>>(ca);

    char* pg0 = p;
    for (int g0 = 0; g0 < NBATCH; g0 += G) {
        const int Mg = G * LSEQ;
        p = pg0;
        unsigned short* xbf   = (unsigned short*)take((size_t)Mg * 512 * 2);
        float* xc_f           = (float*)take((size_t)Mg * 1024 * 4);
        float* z_f            = (float*)take((size_t)Mg * 1024 * 4);
        unsigned short* xiy_f = (unsigned short*)take((size_t)Mg * 1024 * 2);
        float* dbl_f          = (float*)take((size_t)Mg * 64 * 4);
        unsigned short* dblh_f= (unsigned short*)take((size_t)Mg * 32 * 2);
        unsigned short* o_f   = (unsigned short*)take((size_t)Mg * 512 * 2);
        float* xc_b           = (float*)take((size_t)Mg * 1024 * 4);
        float* z_b            = (float*)take((size_t)Mg * 1024 * 4);
        unsigned short* xiy_b = (unsigned short*)take((size_t)Mg * 1024 * 2);
        float* dbl_b          = (float*)take((size_t)Mg * 64 * 4);
        unsigned short* dblh_b= (unsigned short*)take((size_t)Mg * 32 * 2);
        unsigned short* o_b   = (unsigned short*)take((size_t)Mg * 512 * 2);

        const float* xg = x + (size_t)g0 * LSEQ * 512;
        float* outg = out + (size_t)g0 * LSEQ * 512;

        cvtx_k<<<dim3(512), 256, 0, stream>>>(xg, xbf, Mg * 512 / 4);

        // in-proj: x half -> xc, z half -> z (fp32 out)
        gemm_mfma<2,2,0,0,0><<<dim3(8, Mg/128), 256, 0, stream>>>(xbf, 512, nullptr, wif, 512, nullptr, xc_f, 1024, nullptr, 512);
        gemm_mfma<2,2,0,0,0><<<dim3(8, Mg/128), 256, 0, stream>>>(xbf, 512, nullptr, wif + (size_t)1024*512, 512, nullptr, z_f, 1024, nullptr, 512);
        gemm_mfma<2,2,0,0,0><<<dim3(8, Mg/128), 256, 0, stream>>>(xbf, 512, nullptr, wib, 512, nullptr, xc_b, 1024, nullptr, 512);
        gemm_mfma<2,2,0,0,0><<<dim3(8, Mg/128), 256, 0, stream>>>(xbf, 512, nullptr, wib + (size_t)1024*512, 512, nullptr, z_b, 1024, nullptr, 512);

        // conv + SiLU -> bf16 xi
        conv_silu_k<<<dim3(Mg, 2), 256, 0, stream>>>(xc_f, f_cw, f_cb, xiy_f, xc_b, b_cw, b_cb, xiy_b);

        // x-proj: dbl fp32 (ldc 64) + bf16 copy of cols<32 (dblh)
        gemm_mfma<4,1,0,0,1><<<dim3(1, Mg/256), 256, 0, stream>>>(xiy_f, 1024, nullptr, wxf, 1024, nullptr, dbl_f, 64, dblh_f, 1024);
        gemm_mfma<4,1,0,0,1><<<dim3(1, Mg/256), 256, 0, stream>>>(xiy_b, 1024, nullptr, wxb, 1024, nullptr, dbl_b, 64, dblh_b, 1024);

        // dt = softplus(dblh @ dt_w^T + dt_b) -> fp32 into dead xc
        gemm_mfma<2,2,2,0,0><<<dim3(8, Mg/128), 256, 0, stream>>>(dblh_f, 32, nullptr, wdtf, 32, f_dtb, xc_f, 1024, nullptr, 32);
        gemm_mfma<2,2,2,0,0><<<dim3(8, Mg/128), 256, 0, stream>>>(dblh_b, 32, nullptr, wdtb, 32, b_dtb, xc_b, 1024, nullptr, 32);

        // scan + gate -> bf16 y in place over xi
        scan_k<<<dim3(64, G, 2), 256, 0, stream>>>(xc_f, xiy_f, dbl_f, z_f, f_Al, f_Dp,
                                                   xc_b, xiy_b, dbl_b, z_b, b_Al, b_Dp);

        // out-proj: o = y @ out_w^T -> bf16
        gemm_mfma<2,2,1,0,0><<<dim3(4, Mg/128), 256, 0, stream>>>(xiy_f, 1024, nullptr, wof, 1024, nullptr, o_f, 512, nullptr, 1024);
        gemm_mfma<2,2,1,0,0><<<dim3(4, Mg/128), 256, 0, stream>>>(xiy_b, 1024, nullptr, wob, 1024, nullptr, o_b, 512, nullptr, 1024);

        // final: out = [o_f | rev(o_b)] @ lin_w^T + lin_b
        gemm_mfma<2,2,0,1,0><<<dim3(4, Mg/128), 256, 0, stream>>>(o_f, 512, o_b, wlin, 1024, lin_b, outg, 512, nullptr, 1024);
    }
}

// Round 4
// 1030.240 us; speedup vs baseline: 3.4999x; 1.2075x over previous
//
#include <hip/hip_runtime.h>
#include <cmath>

#define LSEQ 2048
#define NBATCH 8

typedef __attribute__((ext_vector_type(8))) short short8;
typedef __attribute__((ext_vector_type(4))) float f32x4;

__device__ __forceinline__ float silu_f(float x) { return x / (1.0f + __expf(-x)); }
__device__ __forceinline__ float softplus_f(float x) {
    return fmaxf(x, 0.0f) + log1pf(__expf(-fabsf(x)));
}
__device__ __forceinline__ unsigned short f2bf(float f) {   // RNE fp32->bf16
    unsigned int u = __float_as_uint(f);
    u += 0x7FFFu + ((u >> 16) & 1u);
    return (unsigned short)(u >> 16);
}
__device__ __forceinline__ float bf2f(unsigned short h) {
    return __uint_as_float(((unsigned int)h) << 16);
}
__device__ __forceinline__ void gload_lds16(const void* g, void* l) {
    __builtin_amdgcn_global_load_lds((const __attribute__((address_space(1))) void*)g,
                                     (__attribute__((address_space(3))) void*)l, 16, 0, 0);
}
// sum over 16-lane row via DPP (VALU pipe, no DS traffic)
__device__ __forceinline__ float row_sum16(float x) {
    x += __int_as_float(__builtin_amdgcn_update_dpp(0, __float_as_int(x), 0xB1, 0xF, 0xF, false));  // quad xor1
    x += __int_as_float(__builtin_amdgcn_update_dpp(0, __float_as_int(x), 0x4E, 0xF, 0xF, false));  // quad xor2
    x += __int_as_float(__builtin_amdgcn_update_dpp(0, __float_as_int(x), 0x141, 0xF, 0xF, false)); // row_half_mirror
    x += __int_as_float(__builtin_amdgcn_update_dpp(0, __float_as_int(x), 0x140, 0xF, 0xF, false)); // row_mirror
    return x;
}

// fwd/bwd operand pairs; blockIdx.z selects direction
struct GemmPair {
    const unsigned short* A[2];
    const unsigned short* A2[2];   // DUAL second A (K-half, row-reversed)
    const unsigned short* W[2];
    const float* bias[2];
    void* C[2];
    unsigned short* aux[2];
};

// ---------------------------------------------------------------------------
// bf16 MFMA GEMM (NT): C[m,n] = act( A[m,:].W[n,:] + bias[n] )
// 256 thr = 4 waves; each wave 64x64 via 4x4 mfma_f32_16x16x32_bf16. BK=32.
// blockIdx.x = m-tile (XCD locality: gridDim.x % 8 == 0 keeps same-A blocks
// on one XCD), blockIdx.y = n-tile, blockIdx.z = direction.
// OMODE: 0=f32, 1=bf16, 2=f32+softplus, 3=bf16+softplus.
// DUAL: k>=512 reads A2 at row^2047 (final merge). XTRA: bf16 copy of cols<32.
// ---------------------------------------------------------------------------
template<int WM, int WN, int OMODE, int DUAL, int XTRA>
__global__ __launch_bounds__(256) void gemm_mfma(GemmPair gp, int lda, int ldw,
                                                 int ldc, int K)
{
    constexpr int TM = WM * 64, TN = WN * 64;
    __shared__ unsigned short As[TM * 32];
    __shared__ unsigned short Bs[TN * 32];
    const int dir = blockIdx.z;
    const unsigned short* A  = gp.A[dir];
    const unsigned short* A2 = gp.A2[dir];
    const unsigned short* W  = gp.W[dir];
    const float* bias        = gp.bias[dir];
    void* Cout               = gp.C[dir];
    unsigned short* aux      = gp.aux[dir];

    const int tid = threadIdx.x;
    const int wave = tid >> 6, lane = tid & 63;
    const int wm = (WN == 1) ? wave : (wave >> 1);
    const int wn = (WN == 1) ? 0 : (wave & 1);
    const int m0 = blockIdx.x * TM, n0 = blockIdx.y * TN;
    const int l15 = lane & 15, l4 = lane >> 4;
    const int srow = lane >> 2, schunk = (lane & 3) * 8;

    f32x4 acc[4][4] = {};

    for (int k0 = 0; k0 < K; k0 += 32) {
        __syncthreads();
        for (int s = wave; s < TM / 16; s += 4) {
            const int gr = m0 + s * 16 + srow;
            const unsigned short* g;
            if (DUAL && k0 >= 512)
                g = A2 + (size_t)(gr ^ (LSEQ - 1)) * 512 + (k0 - 512) + schunk;
            else
                g = A + (size_t)gr * lda + k0 + schunk;
            gload_lds16(g, (char*)As + (size_t)s * 1024);
        }
        for (int s = wave; s < TN / 16; s += 4) {
            const int gr = n0 + s * 16 + srow;
            const unsigned short* g = W + (size_t)gr * ldw + k0 + schunk;
            gload_lds16(g, (char*)Bs + (size_t)s * 1024);
        }
        __syncthreads();
        short8 af[4], bfr[4];
#pragma unroll
        for (int mi = 0; mi < 4; ++mi)
            af[mi] = *(const short8*)&As[(wm * 64 + mi * 16 + l15) * 32 + l4 * 8];
#pragma unroll
        for (int ni = 0; ni < 4; ++ni)
            bfr[ni] = *(const short8*)&Bs[(wn * 64 + ni * 16 + l15) * 32 + l4 * 8];
#pragma unroll
        for (int mi = 0; mi < 4; ++mi)
#pragma unroll
            for (int ni = 0; ni < 4; ++ni)
                acc[mi][ni] = __builtin_amdgcn_mfma_f32_16x16x32_bf16(af[mi], bfr[ni], acc[mi][ni], 0, 0, 0);
    }

#pragma unroll
    for (int mi = 0; mi < 4; ++mi)
#pragma unroll
        for (int ni = 0; ni < 4; ++ni)
#pragma unroll
            for (int r = 0; r < 4; ++r) {
                const int row = m0 + wm * 64 + mi * 16 + l4 * 4 + r;
                const int col = n0 + wn * 64 + ni * 16 + l15;
                float v = acc[mi][ni][r];
                if (bias) v += bias[col];
                if (OMODE >= 2) v = softplus_f(v);
                if (OMODE & 1) ((unsigned short*)Cout)[(size_t)row * ldc + col] = f2bf(v);
                else           ((float*)Cout)[(size_t)row * ldc + col] = v;
                if (XTRA) { if (col < 32) aux[(size_t)row * 32 + col] = f2bf(v); }
            }
}

// ---------------------------------------------------------------------------
// fp32 -> bf16 conversion: 9 weight segments, one launch.
// ---------------------------------------------------------------------------
struct CvtArgs { const float* s[9]; unsigned short* d[9]; int n[9]; };
__global__ __launch_bounds__(256) void cvt_k(CvtArgs a)
{
    const int sid = blockIdx.y;
    const float* s = a.s[sid];
    unsigned short* d = a.d[sid];
    const int n4 = a.n[sid] >> 2;
    for (int i = blockIdx.x * 256 + threadIdx.x; i < n4; i += gridDim.x * 256) {
        const float4 v = ((const float4*)s)[i];
        ushort4 o; o.x = f2bf(v.x); o.y = f2bf(v.y); o.z = f2bf(v.z); o.w = f2bf(v.w);
        ((ushort4*)d)[i] = o;
    }
}
__global__ __launch_bounds__(256) void cvtx_k(const float* __restrict__ s,
                                              unsigned short* __restrict__ d, int n4)
{
    for (int i = blockIdx.x * 256 + threadIdx.x; i < n4; i += gridDim.x * 256) {
        const float4 v = ((const float4*)s)[i];
        ushort4 o; o.x = f2bf(v.x); o.y = f2bf(v.y); o.z = f2bf(v.z); o.w = f2bf(v.w);
        ((ushort4*)d)[i] = o;
    }
}

// ---------------------------------------------------------------------------
// Causal depthwise conv(4) + bias + SiLU, both dirs; bf16 in (xz cols 0..1023,
// ld 2048), bf16 out. Backward dir indexes reversed rows.
// ---------------------------------------------------------------------------
__global__ __launch_bounds__(256) void conv_silu_k(
    const unsigned short* __restrict__ xz_f, const float* __restrict__ cw_f,
    const float* __restrict__ cb_f, unsigned short* __restrict__ xi_f,
    const unsigned short* __restrict__ xz_b, const float* __restrict__ cw_b,
    const float* __restrict__ cb_b, unsigned short* __restrict__ xi_b)
{
    const int dir = blockIdx.y;
    const unsigned short* xz = dir ? xz_b : xz_f;
    const float* cw = dir ? cw_b : cw_f;
    const float* cb = dir ? cb_b : cb_f;
    unsigned short* xi = dir ? xi_b : xi_f;

    const int bt = blockIdx.x;
    const int b = bt >> 11;
    const int t = bt & (LSEQ - 1);
    const int d = threadIdx.x << 2;

    float w[4][4];
#pragma unroll
    for (int i = 0; i < 4; ++i) {
        const float4 wr = *(const float4*)&cw[(d + i) * 4];
        w[i][0] = wr.x; w[i][1] = wr.y; w[i][2] = wr.z; w[i][3] = wr.w;
    }
    float4 acc = *(const float4*)&cb[d];
#pragma unroll
    for (int k = 0; k < 4; ++k) {
        const int row = dir ? (LSEQ - 1 - t) + 3 - k : t - 3 + k;
        if ((unsigned)row < (unsigned)LSEQ) {
            const ushort4 v = *(const ushort4*)&xz[(size_t)(b * LSEQ + row) * 2048 + d];
            acc.x += w[0][k] * bf2f(v.x); acc.y += w[1][k] * bf2f(v.y);
            acc.z += w[2][k] * bf2f(v.z); acc.w += w[3][k] * bf2f(v.w);
        }
    }
    ushort4 st;
    st.x = f2bf(silu_f(acc.x)); st.y = f2bf(silu_f(acc.y));
    st.z = f2bf(silu_f(acc.z)); st.w = f2bf(silu_f(acc.w));
    *(ushort4*)&xi[(size_t)(b * LSEQ + t) * 1024 + d] = st;
}

// ---------------------------------------------------------------------------
// Selective scan. 256 thr = 16 ch x 16 states. LDS transposed [ch][t] ->
// b128 operand reads; state reduction via DPP. dt/xi bf16; z = xz cols 1024+
// (bf16); dbl (B,C) fp32. Writes gated y bf16 in place over xi.
// ---------------------------------------------------------------------------
__global__ __launch_bounds__(256) void scan_k(
    const unsigned short* __restrict__ dt_f, unsigned short* __restrict__ xiy_f,
    const float* __restrict__ dbl_f, const unsigned short* __restrict__ xz_f,
    const float* __restrict__ Al_f, const float* __restrict__ Dp_f,
    const unsigned short* __restrict__ dt_b, unsigned short* __restrict__ xiy_b,
    const float* __restrict__ dbl_b, const unsigned short* __restrict__ xz_b,
    const float* __restrict__ Al_b, const float* __restrict__ Dp_b)
{
    __shared__ float sdt[16][68], sxi[16][68], sB[16][68], sC[16][68], sy[16][68];

    const int dir = blockIdx.z;
    const unsigned short* dt = dir ? dt_b : dt_f;
    unsigned short* xiy = dir ? xiy_b : xiy_f;
    const float* dbl = dir ? dbl_b : dbl_f;
    const unsigned short* zz = dir ? xz_b : xz_f;
    const float* Al = dir ? Al_b : Al_f;
    const float* Dpp = dir ? Dp_b : Dp_f;

    const int b = blockIdx.y, d0 = blockIdx.x << 4;
    const int tid = threadIdx.x;
    const int di = tid >> 4, n = tid & 15;
    const float Av = -expf(Al[(d0 + di) * 16 + n]);
    const int lr = tid >> 2, lc4 = (tid & 3) << 2;
    float dpv[4];
#pragma unroll
    for (int i = 0; i < 4; ++i) dpv[i] = Dpp[d0 + lc4 + i];

    float h = 0.0f;
    for (int t0 = 0; t0 < LSEQ; t0 += 64) {
        __syncthreads();
        const size_t r = (size_t)b * LSEQ + t0 + lr;
        const ushort4 dv = *(const ushort4*)&dt[r * 1024 + d0 + lc4];
        const ushort4 xv = *(const ushort4*)&xiy[r * 1024 + d0 + lc4];
        const float4 bv = *(const float4*)&dbl[r * 64 + 32 + lc4];
        const float4 cv = *(const float4*)&dbl[r * 64 + 48 + lc4];
        sdt[lc4 + 0][lr] = bf2f(dv.x); sdt[lc4 + 1][lr] = bf2f(dv.y);
        sdt[lc4 + 2][lr] = bf2f(dv.z); sdt[lc4 + 3][lr] = bf2f(dv.w);
        sxi[lc4 + 0][lr] = bf2f(xv.x); sxi[lc4 + 1][lr] = bf2f(xv.y);
        sxi[lc4 + 2][lr] = bf2f(xv.z); sxi[lc4 + 3][lr] = bf2f(xv.w);
        sB[lc4 + 0][lr] = bv.x; sB[lc4 + 1][lr] = bv.y; sB[lc4 + 2][lr] = bv.z; sB[lc4 + 3][lr] = bv.w;
        sC[lc4 + 0][lr] = cv.x; sC[lc4 + 1][lr] = cv.y; sC[lc4 + 2][lr] = cv.z; sC[lc4 + 3][lr] = cv.w;
        __syncthreads();

#pragma unroll
        for (int tt = 0; tt < 64; tt += 4) {
            const float4 d4 = *(const float4*)&sdt[di][tt];
            const float4 x4 = *(const float4*)&sxi[di][tt];
            const float4 b4 = *(const float4*)&sB[n][tt];
            const float4 c4 = *(const float4*)&sC[n][tt];
            {
                h = fmaf(__expf(d4.x * Av), h, d4.x * x4.x * b4.x);
                const float pp = row_sum16(h * c4.x);
                if (n == 0) sy[di][tt + 0] = pp;
            }
            {
                h = fmaf(__expf(d4.y * Av), h, d4.y * x4.y * b4.y);
                const float pp = row_sum16(h * c4.y);
                if (n == 0) sy[di][tt + 1] = pp;
            }
            {
                h = fmaf(__expf(d4.z * Av), h, d4.z * x4.z * b4.z);
                const float pp = row_sum16(h * c4.z);
                if (n == 0) sy[di][tt + 2] = pp;
            }
            {
                h = fmaf(__expf(d4.w * Av), h, d4.w * x4.w * b4.w);
                const float pp = row_sum16(h * c4.w);
                if (n == 0) sy[di][tt + 3] = pp;
            }
        }
        __syncthreads();

        float4 y4, xi4;
        y4.x = sy[lc4 + 0][lr]; y4.y = sy[lc4 + 1][lr]; y4.z = sy[lc4 + 2][lr]; y4.w = sy[lc4 + 3][lr];
        xi4.x = sxi[lc4 + 0][lr]; xi4.y = sxi[lc4 + 1][lr]; xi4.z = sxi[lc4 + 2][lr]; xi4.w = sxi[lc4 + 3][lr];
        const int tz = dir ? (LSEQ - 1 - (t0 + lr)) : (t0 + lr);
        const ushort4 z4 = *(const ushort4*)&zz[((size_t)b * LSEQ + tz) * 2048 + 1024 + d0 + lc4];
        ushort4 st;
        st.x = f2bf((y4.x + xi4.x * dpv[0]) * silu_f(bf2f(z4.x)));
        st.y = f2bf((y4.y + xi4.y * dpv[1]) * silu_f(bf2f(z4.y)));
        st.z = f2bf((y4.z + xi4.z * dpv[2]) * silu_f(bf2f(z4.z)));
        st.w = f2bf((y4.w + xi4.w * dpv[3]) * silu_f(bf2f(z4.w)));
        *(ushort4*)&xiy[r * 1024 + d0 + lc4] = st;
    }
}

// ---------------------------------------------------------------------------
extern "C" void kernel_launch(void* const* d_in, const int* in_sizes, int n_in,
                              void* d_out, int out_size, void* d_ws, size_t ws_size,
                              hipStream_t stream)
{
    const float* x      = (const float*)d_in[0];
    const float* f_in_w = (const float*)d_in[1];
    const float* f_cw   = (const float*)d_in[2];
    const float* f_cb   = (const float*)d_in[3];
    const float* f_xp   = (const float*)d_in[4];
    const float* f_dtw  = (const float*)d_in[5];
    const float* f_dtb  = (const float*)d_in[6];
    const float* f_Al   = (const float*)d_in[7];
    const float* f_Dp   = (const float*)d_in[8];
    const float* f_ow   = (const float*)d_in[9];
    const float* b_in_w = (const float*)d_in[10];
    const float* b_cw   = (const float*)d_in[11];
    const float* b_cb   = (const float*)d_in[12];
    const float* b_xp   = (const float*)d_in[13];
    const float* b_dtw  = (const float*)d_in[14];
    const float* b_dtb  = (const float*)d_in[15];
    const float* b_Al   = (const float*)d_in[16];
    const float* b_Dp   = (const float*)d_in[17];
    const float* b_ow   = (const float*)d_in[18];
    const float* lin_w  = (const float*)d_in[19];
    const float* lin_b  = (const float*)d_in[20];
    float* out = (float*)d_out;

    char* p = (char*)d_ws;
    auto take = [&](size_t bytes) -> char* {
        char* r = p; p += (bytes + 255) & ~(size_t)255; return r;
    };

    // persistent bf16 weights
    unsigned short* wif  = (unsigned short*)take((size_t)2048 * 512 * 2);
    unsigned short* wib  = (unsigned short*)take((size_t)2048 * 512 * 2);
    unsigned short* wxf  = (unsigned short*)take((size_t)64 * 1024 * 2);
    unsigned short* wxb  = (unsigned short*)take((size_t)64 * 1024 * 2);
    unsigned short* wof  = (unsigned short*)take((size_t)512 * 1024 * 2);
    unsigned short* wob  = (unsigned short*)take((size_t)512 * 1024 * 2);
    unsigned short* wlin = (unsigned short*)take((size_t)512 * 1024 * 2);
    unsigned short* wdtf = (unsigned short*)take((size_t)1024 * 32 * 2);
    unsigned short* wdtb = (unsigned short*)take((size_t)1024 * 32 * 2);

    const size_t used = (size_t)(p - (char*)d_ws);
    // per-row bytes: xbf 1024 + per dir (xz 4096 + xiy 2048 + dbl 256 + dblh 64 + dt 2048 + o 1024)
    const size_t perRow = 1024 + 2 * (4096 + 2048 + 256 + 64 + 2048 + 1024);
    int G = 1;
    for (int g = 8; g >= 1; g >>= 1) {
        const size_t need = used + (size_t)g * LSEQ * perRow + 16384;
        if (need <= ws_size || g == 1) { G = g; break; }
    }

    CvtArgs ca;
    ca.s[0] = f_in_w; ca.d[0] = wif;  ca.n[0] = 2048 * 512;
    ca.s[1] = b_in_w; ca.d[1] = wib;  ca.n[1] = 2048 * 512;
    ca.s[2] = f_xp;   ca.d[2] = wxf;  ca.n[2] = 64 * 1024;
    ca.s[3] = b_xp;   ca.d[3] = wxb;  ca.n[3] = 64 * 1024;
    ca.s[4] = f_ow;   ca.d[4] = wof;  ca.n[4] = 512 * 1024;
    ca.s[5] = b_ow;   ca.d[5] = wob;  ca.n[5] = 512 * 1024;
    ca.s[6] = lin_w;  ca.d[6] = wlin; ca.n[6] = 512 * 1024;
    ca.s[7] = f_dtw;  ca.d[7] = wdtf; ca.n[7] = 1024 * 32;
    ca.s[8] = b_dtw;  ca.d[8] = wdtb; ca.n[8] = 1024 * 32;
    cvt_k<<<dim3(256, 9), 256, 0, stream>>>(ca);

    char* pg0 = p;
    for (int g0 = 0; g0 < NBATCH; g0 += G) {
        const int Mg = G * LSEQ;
        p = pg0;
        unsigned short* xbf   = (unsigned short*)take((size_t)Mg * 512 * 2);
        unsigned short* xz_f  = (unsigned short*)take((size_t)Mg * 2048 * 2);
        unsigned short* xz_b  = (unsigned short*)take((size_t)Mg * 2048 * 2);
        unsigned short* xiy_f = (unsigned short*)take((size_t)Mg * 1024 * 2);
        unsigned short* xiy_b = (unsigned short*)take((size_t)Mg * 1024 * 2);
        float* dbl_f          = (float*)take((size_t)Mg * 64 * 4);
        float* dbl_b          = (float*)take((size_t)Mg * 64 * 4);
        unsigned short* dblh_f= (unsigned short*)take((size_t)Mg * 32 * 2);
        unsigned short* dblh_b= (unsigned short*)take((size_t)Mg * 32 * 2);
        unsigned short* dt_f  = (unsigned short*)take((size_t)Mg * 1024 * 2);
        unsigned short* dt_b  = (unsigned short*)take((size_t)Mg * 1024 * 2);
        unsigned short* o_f   = (unsigned short*)take((size_t)Mg * 512 * 2);
        unsigned short* o_b   = (unsigned short*)take((size_t)Mg * 512 * 2);

        const float* xg = x + (size_t)g0 * LSEQ * 512;
        float* outg = out + (size_t)g0 * LSEQ * 512;

        cvtx_k<<<dim3(512), 256, 0, stream>>>(xg, xbf, Mg * 512 / 4);

        GemmPair g1 = {};   // in-proj: xz = x @ in_w^T (N=2048), bf16 out
        g1.A[0] = xbf; g1.A[1] = xbf; g1.W[0] = wif; g1.W[1] = wib;
        g1.C[0] = xz_f; g1.C[1] = xz_b;
        gemm_mfma<2,2,1,0,0><<<dim3(Mg/128, 16, 2), 256, 0, stream>>>(g1, 512, 512, 2048, 512);

        conv_silu_k<<<dim3(Mg, 2), 256, 0, stream>>>(xz_f, f_cw, f_cb, xiy_f,
                                                     xz_b, b_cw, b_cb, xiy_b);

        GemmPair g2 = {};   // x-proj: dbl (f32, ldc 64) + bf16 cols<32 (dblh)
        g2.A[0] = xiy_f; g2.A[1] = xiy_b; g2.W[0] = wxf; g2.W[1] = wxb;
        g2.C[0] = dbl_f; g2.C[1] = dbl_b; g2.aux[0] = dblh_f; g2.aux[1] = dblh_b;
        gemm_mfma<4,1,0,0,1><<<dim3(Mg/256, 1, 2), 256, 0, stream>>>(g2, 1024, 1024, 64, 1024);

        GemmPair g3 = {};   // dt = softplus(dblh @ dt_w^T + dt_b), bf16 out
        g3.A[0] = dblh_f; g3.A[1] = dblh_b; g3.W[0] = wdtf; g3.W[1] = wdtb;
        g3.bias[0] = f_dtb; g3.bias[1] = b_dtb; g3.C[0] = dt_f; g3.C[1] = dt_b;
        gemm_mfma<2,2,3,0,0><<<dim3(Mg/128, 8, 2), 256, 0, stream>>>(g3, 32, 32, 1024, 32);

        scan_k<<<dim3(64, G, 2), 256, 0, stream>>>(dt_f, xiy_f, dbl_f, xz_f, f_Al, f_Dp,
                                                   dt_b, xiy_b, dbl_b, xz_b, b_Al, b_Dp);

        GemmPair g4 = {};   // out-proj: o = y @ out_w^T, bf16 out
        g4.A[0] = xiy_f; g4.A[1] = xiy_b; g4.W[0] = wof; g4.W[1] = wob;
        g4.C[0] = o_f; g4.C[1] = o_b;
        gemm_mfma<2,2,1,0,0><<<dim3(Mg/128, 4, 2), 256, 0, stream>>>(g4, 1024, 1024, 512, 1024);

        GemmPair g5 = {};   // final: out = [o_f | rev(o_b)] @ lin_w^T + lin_b, f32 out
        g5.A[0] = o_f; g5.A2[0] = o_b; g5.W[0] = wlin; g5.bias[0] = lin_b; g5.C[0] = outg;
        gemm_mfma<2,2,0,1,0><<<dim3(Mg/128, 4, 1), 256, 0, stream>>>(g5, 512, 1024, 512, 1024);
    }
}